// Round 5
// baseline (962.781 us; speedup 1.0000x reference)
//
#include <hip/hip_runtime.h>
#include <hip/hip_bf16.h>

#define N_NODES 100000
#define N_EDGES 3200000
#define FIN 512
#define FOUT 256
#define GEMM_BM 128
#define GEMM_BK 32

#define SCAN_BLKS 98           // ceil(100000/1024)

typedef __attribute__((ext_vector_type(8))) short short8;
typedef __attribute__((ext_vector_type(4))) float f32x4;

__device__ __forceinline__ unsigned short f2bf(float f) {
    unsigned u = __float_as_uint(f);
    u += 0x7fffu + ((u >> 16) & 1u);      // RNE to bf16
    return (unsigned short)(u >> 16);
}
__device__ __forceinline__ float bf2f(unsigned short h) {
    return __uint_as_float(((unsigned)h) << 16);
}

// direct-to-LDS 16B async copy (lds dest must be wave-uniform; HW adds lane*16)
__device__ __forceinline__ void gload_lds16(const void* g, void* l) {
    __builtin_amdgcn_global_load_lds(
        (const __attribute__((address_space(1))) unsigned*)g,
        (__attribute__((address_space(3))) unsigned*)l, 16, 0, 0);
}

// ---------------------------------------------------------------------------
// Kernel 1: W [512][256] fp32 -> Wt bf16 as one 16KB chunk per K-step
// (k in [32s,32s+32), all 256 n), LDS-image-linear for global_load_lds with
// the ds_read bank-conflict XOR swizzle baked in:
//   short offset = s*8192 + n*32 + u*8 + (k&7),
//   u = (kk>>3) ^ (n&3) ^ ((n>>2)&3)   (bijective in the 16B-unit index)
// ---------------------------------------------------------------------------
__global__ __launch_bounds__(256) void prep_weight(const float* __restrict__ W,
                                                   unsigned short* __restrict__ Wt) {
    int idx = blockIdx.x * 256 + threadIdx.x;
    if (idx < FIN * FOUT) {
        int k = idx >> 8;        // 0..511
        int n = idx & 255;       // 0..255
        int s = k >> 5;          // K-step
        int kk = k & 31;
        int kb16 = kk >> 3;      // which 16B unit (8 shorts) of the 64B k-row
        int u = kb16 ^ (n & 3) ^ ((n >> 2) & 3);
        Wt[(size_t)s * 8192 + n * 32 + u * 8 + (kk & 7)] = f2bf(W[idx]);
    }
}

// ---------------------------------------------------------------------------
// Kernel 2: support(bf16) = bf16(X @ W). BM=128 x BN=256(full) x BK=32,
// 512 threads = 8 waves; wave (wm,wn) owns rows [64wm,+64) x cols [64wn,+64).
// X read once. A: fp32 global -> regs -> bf16 -> padded LDS. B:
// global_load_lds width=16 from pre-swizzled Wt; swizzle undone on ds_read.
// (unchanged from round 4 — isolating the sort-pipeline change)
// ---------------------------------------------------------------------------
__global__ __launch_bounds__(512, 2)
void gemm_kernel(const float* __restrict__ X, const unsigned short* __restrict__ Wt,
                 unsigned short* __restrict__ support) {
    __shared__ unsigned short A_lds[GEMM_BM][40];          // 10 KB, pad 40 (proven)
    __shared__ __align__(16) unsigned short bls[8192];     // 16 KB, B chunk image

    const int t = threadIdx.x;
    const int lane = t & 63;
    const int w = t >> 6;         // 0..7
    const int wm = w >> 2;        // 0..1  (M half)
    const int wn = w & 3;         // 0..3  (N quarter)
    const int q = lane >> 4;
    const int lr = lane & 15;
    const int m0 = blockIdx.x * GEMM_BM;

    f32x4 acc[4][4];
#pragma unroll
    for (int i = 0; i < 4; i++)
#pragma unroll
        for (int j = 0; j < 4; j++) acc[i][j] = (f32x4)0.0f;

    const int arow = t >> 2;            // 0..127, 4 threads per A row
    const int acol = (t & 3) * 8;       // 8 fp32 each
    const bool avalid = (m0 + arow) < N_NODES;
    const float* Xp = X + (size_t)(m0 + arow) * FIN + acol;

    // B global source: chunk s is contiguous 16KB; thread t carries 16B at t*16
    const unsigned short* gB = Wt + t * 8;
    unsigned short* ldsB0 = &bls[w * 512];            // wave-uniform dest
    unsigned short* ldsB1 = &bls[4096 + w * 512];     // second 8KB half

    for (int s = 0; s < FIN / GEMM_BK; ++s) {
        // ---- A tile: global fp32 -> regs -> bf16 (overlaps prior MFMA) ----
        union { __hip_bfloat162 h[4]; uint4 v; } pk;
        if (avalid) {
            float4 v0 = *(const float4*)(Xp + s * GEMM_BK);
            float4 v1 = *(const float4*)(Xp + s * GEMM_BK + 4);
            pk.h[0] = __float22bfloat162_rn(make_float2(v0.x, v0.y));
            pk.h[1] = __float22bfloat162_rn(make_float2(v0.z, v0.w));
            pk.h[2] = __float22bfloat162_rn(make_float2(v1.x, v1.y));
            pk.h[3] = __float22bfloat162_rn(make_float2(v1.z, v1.w));
        } else {
            pk.v = make_uint4(0, 0, 0, 0);
        }

        __syncthreads();   // protect prior iteration's fragment reads

        // ---- B tile: 16KB direct to LDS (2 x 8KB issues), no reg roundtrip ----
        gload_lds16(gB + (size_t)s * 8192, ldsB0);
        gload_lds16(gB + (size_t)s * 8192 + 4096, ldsB1);

        *(uint4*)&A_lds[arow][acol] = pk.v;

        __syncthreads();   // compiler drains vmcnt(0)+lgkmcnt(0) here: B+A ready

        short8 af[4], bfr[4];
#pragma unroll
        for (int i = 0; i < 4; i++) af[i] = *(const short8*)&A_lds[wm * 64 + i * 16 + lr][q * 8];
#pragma unroll
        for (int j = 0; j < 4; j++) {
            int nl = wn * 64 + j * 16 + lr;              // 0..255
            int u = q ^ (nl & 3) ^ ((nl >> 2) & 3);      // undo the baked swizzle
            bfr[j] = *(const short8*)&bls[nl * 32 + u * 8];
        }
#pragma unroll
        for (int i = 0; i < 4; i++)
#pragma unroll
            for (int j = 0; j < 4; j++)
                acc[i][j] = __builtin_amdgcn_mfma_f32_16x16x32_bf16(af[i], bfr[j], acc[i][j], 0, 0, 0);
    }

#pragma unroll
    for (int i = 0; i < 4; i++) {
#pragma unroll
        for (int r = 0; r < 4; r++) {
            int gm = m0 + wm * 64 + i * 16 + q * 4 + r;
            if (gm < N_NODES) {
#pragma unroll
                for (int j = 0; j < 4; j++)
                    support[(size_t)gm * FOUT + wn * 64 + j * 16 + lr] = f2bf(acc[i][j][r]);
            }
        }
    }
}

// ---------------------------------------------------------------------------
// Kernel 3: per-node histogram. 3.2M global atomics into 400KB (L2-resident,
// avg 32 increments/address -> low contention).
// ---------------------------------------------------------------------------
__global__ __launch_bounds__(256) void node_hist(const int* __restrict__ row,
                                                 unsigned* __restrict__ cnt) {
    int e = blockIdx.x * 2048 + threadIdx.x;
#pragma unroll
    for (int j = 0; j < 8; ++j, e += 256)
        if (e < N_EDGES) atomicAdd(&cnt[row[e]], 1u);
}

// ---------------------------------------------------------------------------
// Kernel 4a: level-1 scan: 98 blocks x 1024; block-local exclusive scan of
// cnt -> cursor, block totals -> bsum.
// ---------------------------------------------------------------------------
__global__ __launch_bounds__(1024) void scan_l1(const unsigned* __restrict__ cnt,
                                                unsigned* __restrict__ cursor,
                                                unsigned* __restrict__ bsum) {
    __shared__ unsigned s[1024];
    const int t = threadIdx.x;
    const int i = blockIdx.x * 1024 + t;
    unsigned v = (i < N_NODES) ? cnt[i] : 0u;
    s[t] = v;
    __syncthreads();
#pragma unroll
    for (int off = 1; off < 1024; off <<= 1) {
        unsigned tv = (t >= off) ? s[t - off] : 0u;
        __syncthreads();
        s[t] += tv;
        __syncthreads();
    }
    if (i < N_NODES) cursor[i] = s[t] - v;   // block-local exclusive
    if (t == 1023) bsum[blockIdx.x] = s[1023];
}

// ---------------------------------------------------------------------------
// Kernel 4b: level-2 scan of the 98 block totals -> exclusive boff.
// ---------------------------------------------------------------------------
__global__ __launch_bounds__(128) void scan_l2(const unsigned* __restrict__ bsum,
                                               unsigned* __restrict__ boff) {
    __shared__ unsigned s[128];
    const int t = threadIdx.x;
    unsigned v = (t < SCAN_BLKS) ? bsum[t] : 0u;
    s[t] = v;
    __syncthreads();
#pragma unroll
    for (int off = 1; off < 128; off <<= 1) {
        unsigned tv = (t >= off) ? s[t - off] : 0u;
        __syncthreads();
        s[t] += tv;
        __syncthreads();
    }
    if (t < SCAN_BLKS) boff[t] = s[t] - v;
}

// ---------------------------------------------------------------------------
// Kernel 4c: add block offsets; emit row_ptr and cursor (= scatter cursors).
// ---------------------------------------------------------------------------
__global__ __launch_bounds__(1024) void scan_l3(unsigned* __restrict__ cursor,
                                                const unsigned* __restrict__ boff,
                                                unsigned* __restrict__ row_ptr) {
    const int i = blockIdx.x * 1024 + threadIdx.x;
    if (i < N_NODES) {
        unsigned v = cursor[i] + boff[blockIdx.x];
        cursor[i] = v;
        row_ptr[i] = v;
    }
    if (i == 0) row_ptr[N_NODES] = N_EDGES;
}

// ---------------------------------------------------------------------------
// Kernel 5: single-pass counting-sort scatter: each record written ONCE to
// its final dest-sorted position (replaces the two-pass partition machinery:
// 77MB of record movement -> 26MB). Random 8B writes land in a 25.6MB buffer
// <= 32MB aggregate L2 -> lines fill before eviction.
// ---------------------------------------------------------------------------
__global__ __launch_bounds__(256) void node_scatter(const int* __restrict__ row,
                                                    const int* __restrict__ col,
                                                    const float* __restrict__ val,
                                                    unsigned* __restrict__ cursor,
                                                    uint2* __restrict__ part) {
    int e = blockIdx.x * 2048 + threadIdx.x;
#pragma unroll
    for (int j = 0; j < 8; ++j, e += 256)
        if (e < N_EDGES) {
            unsigned pos = atomicAdd(&cursor[row[e]], 1u);
            part[pos] = make_uint2((unsigned)col[e], __float_as_uint(val[e]));
        }
}

// ---------------------------------------------------------------------------
// Kernel 6: SpMM pull, feature-split across TWO DISPATCHES (fb=0,128).
// Lane l owns feats fb+2l..fb+2l+1. Batch-16 software pipeline.
// (unchanged from round 4)
// ---------------------------------------------------------------------------
__global__ __launch_bounds__(256)
void spmm_kernel(const unsigned* __restrict__ row_ptr, const uint2* __restrict__ sorted,
                 const unsigned short* __restrict__ support, const float* __restrict__ bias,
                 float* __restrict__ out, int fb) {
    const int lane = threadIdx.x & 63;
    const int n = blockIdx.x * 4 + (threadIdx.x >> 6);
    const unsigned start = __builtin_amdgcn_readfirstlane(row_ptr[n]);
    const unsigned end   = __builtin_amdgcn_readfirstlane(row_ptr[n + 1]);
    const int fo = fb + lane * 2;
    const unsigned short* sp = support + fo;
    float a0 = 0.f, a1 = 0.f;

    unsigned i = start;
    const unsigned nfull = (end - start) >> 4;
    if (nfull) {
        uint2 e[16];
#pragma unroll
        for (int j = 0; j < 16; ++j) e[j] = sorted[i + j];
        for (unsigned bt = 1; bt < nfull; ++bt) {
            ushort2 s[16];
#pragma unroll
            for (int j = 0; j < 16; ++j) s[j] = *(const ushort2*)(sp + (size_t)e[j].x * FOUT);
            uint2 en[16];
#pragma unroll
            for (int j = 0; j < 16; ++j) en[j] = sorted[i + 16 + j];   // prefetch next batch
#pragma unroll
            for (int j = 0; j < 16; ++j) {
                float v = __uint_as_float(e[j].y);
                a0 += v * bf2f(s[j].x); a1 += v * bf2f(s[j].y);
            }
#pragma unroll
            for (int j = 0; j < 16; ++j) e[j] = en[j];
            i += 16;
        }
        ushort2 s[16];
#pragma unroll
        for (int j = 0; j < 16; ++j) s[j] = *(const ushort2*)(sp + (size_t)e[j].x * FOUT);
#pragma unroll
        for (int j = 0; j < 16; ++j) {
            float v = __uint_as_float(e[j].y);
            a0 += v * bf2f(s[j].x); a1 += v * bf2f(s[j].y);
        }
        i += 16;
    }
    if (end - i >= 8) {
        uint2 e[8];
#pragma unroll
        for (int j = 0; j < 8; ++j) e[j] = sorted[i + j];
        ushort2 s[8];
#pragma unroll
        for (int j = 0; j < 8; ++j) s[j] = *(const ushort2*)(sp + (size_t)e[j].x * FOUT);
#pragma unroll
        for (int j = 0; j < 8; ++j) {
            float v = __uint_as_float(e[j].y);
            a0 += v * bf2f(s[j].x); a1 += v * bf2f(s[j].y);
        }
        i += 8;
    }
    for (; i < end; ++i) {
        uint2 e = sorted[i];
        float v = __uint_as_float(e.y);
        ushort2 s0 = *(const ushort2*)(sp + (size_t)e.x * FOUT);
        a0 += v * bf2f(s0.x); a1 += v * bf2f(s0.y);
    }

    float2 bv = *(const float2*)(bias + fo);
    float2 r;
    r.x = rintf(a0 * 1000.f) * 0.001f + bv.x;
    r.y = rintf(a1 * 1000.f) * 0.001f + bv.y;
    *(float2*)(out + (size_t)n * FOUT + fo) = r;
}

// ---------------------------------------------------------------------------
extern "C" void kernel_launch(void* const* d_in, const int* in_sizes, int n_in,
                              void* d_out, int out_size, void* d_ws, size_t ws_size,
                              hipStream_t stream) {
    (void)in_sizes; (void)n_in; (void)out_size; (void)ws_size;
    const float* X    = (const float*)d_in[0];
    const float* W    = (const float*)d_in[1];
    const float* bias = (const float*)d_in[2];
    const float* eval = (const float*)d_in[3];
    const int*   row  = (const int*)d_in[4];
    const int*   col  = (const int*)d_in[5];
    float* out = (float*)d_out;

    char* p = (char*)d_ws;
    auto take = [&](size_t bytes) {
        char* r = p;
        p += (bytes + 511) & ~(size_t)511;
        return r;
    };
    unsigned short* support = (unsigned short*)take((size_t)N_NODES * FOUT * 2); // 51.2 MB
    unsigned short* Wt      = (unsigned short*)take((size_t)FIN * FOUT * 2);     // 256 KB
    unsigned*       cnt     = (unsigned*)take((size_t)N_NODES * 4);              // 400 KB
    unsigned*       cursor  = (unsigned*)take((size_t)N_NODES * 4);              // 400 KB
    unsigned*       row_ptr = (unsigned*)take((size_t)(N_NODES + 1) * 4);
    unsigned*       bsum    = (unsigned*)take((size_t)SCAN_BLKS * 4);
    unsigned*       boff    = (unsigned*)take((size_t)SCAN_BLKS * 4);
    uint2*          part    = (uint2*)take((size_t)N_EDGES * 8 + 1024);          // 25.6 MB + slack

    hipMemsetAsync(cnt, 0, (size_t)N_NODES * 4, stream);
    prep_weight<<<(FIN * FOUT) / 256, 256, 0, stream>>>(W, Wt);
    gemm_kernel<<<(N_NODES + GEMM_BM - 1) / GEMM_BM, 512, 0, stream>>>(X, Wt, support);
    node_hist<<<(N_EDGES + 2047) / 2048, 256, 0, stream>>>(row, cnt);
    scan_l1<<<SCAN_BLKS, 1024, 0, stream>>>(cnt, cursor, bsum);
    scan_l2<<<1, 128, 0, stream>>>(bsum, boff);
    scan_l3<<<SCAN_BLKS, 1024, 0, stream>>>(cursor, boff, row_ptr);
    node_scatter<<<(N_EDGES + 2047) / 2048, 256, 0, stream>>>(row, col, eval, cursor, part);
    spmm_kernel<<<N_NODES / 4, 256, 0, stream>>>(row_ptr, part, support, bias, out, 0);
    spmm_kernel<<<N_NODES / 4, 256, 0, stream>>>(row_ptr, part, support, bias, out, 128);
}